// Round 14
// baseline (70.119 us; speedup 1.0000x reference)
//
#include <hip/hip_runtime.h>

#define N_ 4096
#define K_ 64
#define E_ (N_*K_)
#define H_ 256
#define EPS_ 1e-5f
#define L2E_ 1.4426950408889634f   // log2(e)
#define TL2E_ 2.8853900817779268f  // 2*log2(e)

#if __has_builtin(__builtin_amdgcn_exp2f)
#define EXP2(x) __builtin_amdgcn_exp2f(x)
#else
#define EXP2(x) __expf((x) * 0.6931471805599453f)
#endif

// tanh(x) = 1 - 2/(2^(2*log2e*x)+1); inf-safe (exp2(+inf)->inf, rcp(inf)=0)
__device__ __forceinline__ float ftanh(float x) {
    float e = EXP2(x * TL2E_);
    return 1.0f - 2.0f * __builtin_amdgcn_rcpf(e + 1.0f);
}

// prep2: 8 blocks x 32-col slices. LDS-tiled W1 (coalesced float4), no atomics,
// no memset. W01g[5*256] = TL2E*{W0@W1; b0@W1+b1}. Block 0: swp = sum(W2)+b2.
// All blocks zero their slice of part[32][512]. (R13-exact.)
__global__ __launch_bounds__(256) void prep2_kernel(
    const float* __restrict__ W0, const float* __restrict__ b0,
    const float* __restrict__ W1, const float* __restrict__ b1,
    const float* __restrict__ W2, const float* __restrict__ b2,
    float* __restrict__ W01g, float* __restrict__ swp, float* __restrict__ part)
{
    __shared__ float LW1[256 * 32];   // [h][c_loc], 32 KB
    __shared__ float W0s[5 * 256];    // W0 rows 0..3 + b0
    __shared__ float red[256];

    const int t = threadIdx.x;
    const int b = blockIdx.x;

    #pragma unroll
    for (int k = 0; k < 8; ++k) part[b * 2048 + k * 256 + t] = 0.f;

    {
        const float4* W1_4 = reinterpret_cast<const float4*>(W1);
        #pragma unroll
        for (int k = 0; k < 8; ++k) {
            int flat = k * 256 + t;
            int h = flat >> 3, j = flat & 7;
            *reinterpret_cast<float4*>(&LW1[h * 32 + 4 * j]) = W1_4[h * 64 + b * 8 + j];
        }
        W0s[t] = W0[t];
        W0s[256 + t] = W0[256 + t];
        W0s[512 + t] = W0[512 + t];
        W0s[768 + t] = W0[768 + t];
        W0s[1024 + t] = b0[t];
        red[t] = W2[t];
    }
    __syncthreads();

    const int role = t >> 5, c = t & 31;
    if (role < 5) {
        const float* wrow = &W0s[role * 256];
        float acc = 0.f;
        #pragma unroll 8
        for (int h = 0; h < 256; ++h) acc = fmaf(wrow[h], LW1[h * 32 + c], acc);
        int cg = b * 32 + c;
        if (role < 4) W01g[role * 256 + cg] = TL2E_ * acc;
        else          W01g[1024 + cg] = TL2E_ * (acc + b1[cg]);
    }

    if (b == 0) {
        __syncthreads();
        for (int s = 128; s > 0; s >>= 1) {
            if (t < s) red[t] += red[t + s];
            __syncthreads();
        }
        if (t == 0) swp[0] = red[0] + b2[0];
    }
}

// stats: R13-exact. Grouped atomicAdd into part[blockIdx&31][col].
__global__ __launch_bounds__(256, 8) void stats_kernel(
    const float* __restrict__ coor, const float* __restrict__ W01g,
    float* __restrict__ part)
{
    const int c = threadIdx.x;
    const float w0 = W01g[c],          w1 = W01g[H_ + c];
    const float w2 = W01g[2 * H_ + c], w3 = W01g[3 * H_ + c];
    const float bb = W01g[4 * H_ + c];
    __shared__ float4 T[128];
    const int e0 = blockIdx.x * 128;
    if (c < 128) {
        float4 v = reinterpret_cast<const float4*>(coor)[e0 + c];
        T[c] = make_float4(ftanh(v.x), ftanh(v.y), ftanh(v.z), ftanh(v.w));
    }
    __syncthreads();
    float sr = 0.f, sr2 = 0.f;
    #pragma unroll 8
    for (int i = 0; i < 128; ++i) {
        float4 t = T[i];
        float u = fmaf(t.w, w3, fmaf(t.z, w2, fmaf(t.y, w1, fmaf(t.x, w0, bb))));
        float r = __builtin_amdgcn_rcpf(EXP2(u) + 1.0f);
        sr += r;
        sr2 = fmaf(r, r, sr2);
    }
    const int g = blockIdx.x & 31;
    atomicAdd(&part[g * 512 + c], sr);
    atomicAdd(&part[g * 512 + 256 + c], sr2);
}

// fold: 1 block. Reduce 32 part-groups, BN-fold, write folded records.
// Moves the 5-7us in-edge fold cost to a ~2us dispatch (R8/R13 vs R11/R12).
__global__ __launch_bounds__(256) void fold_kernel(
    const float* __restrict__ part, const float* __restrict__ W01g,
    const float* __restrict__ gamma, const float* __restrict__ beta,
    const float* __restrict__ W2, float* __restrict__ folded)
{
    const int t = threadIdx.x;
    float sr = 0.f, sr2 = 0.f;
    #pragma unroll 8
    for (int g = 0; g < 32; ++g) {
        sr  += part[g * 512 + t];
        sr2 += part[g * 512 + 256 + t];
    }
    const float inv = 1.0f / (float)E_;
    float sp = sr * inv;
    float sq = sr2 * inv;
    float mu = 1.0f - 2.0f * sp;
    float var = 4.0f * fmaf(-sp, sp, sq);
    float a  = gamma[t] * rsqrtf(var + EPS_);
    float bf = fmaf(-mu, a, beta[t]);
    float4* F = reinterpret_cast<float4*>(folded);
    F[2 * t]     = make_float4(W01g[t], W01g[H_ + t], W01g[2 * H_ + t], W01g[3 * H_ + t]);
    F[2 * t + 1] = make_float4(W01g[4 * H_ + t], -4.0f * L2E_ * a,
                               TL2E_ * (a + bf), -2.0f * W2[t]);
}

// Edge kernel: R12-exact (measured 43.2us). Stage: padded FS from folded,
// tanh SoA, att, COL/ATT, zero-fill. Compute: 8 edges x 16 cols. Tail: LDS
// dedup + hoisted geo/ang + rare-dup mask walk.
__global__ __launch_bounds__(256, 8) void edge_kernel(
    const float* __restrict__ coor, const int* __restrict__ idx,
    const float* __restrict__ folded, const float* __restrict__ swp,
    const float* __restrict__ Wq, const float* __restrict__ bq,
    const float* __restrict__ Wk, const float* __restrict__ bk,
    const float* __restrict__ geo, const float* __restrict__ ang,
    float* __restrict__ out)
{
    __shared__ float4 FS[2 * H_ + 16];  // padded: float4 j at j+(j>>5)
    __shared__ float  TSx[128], TSy[128], TSz[128], TSw[128];
    __shared__ float  ACC[16][128];
    __shared__ int    COL[128];
    __shared__ float  ATT[128];

    const int t = threadIdx.x;
    const int row0 = blockIdx.x * 2;
    const int eb0 = blockIdx.x * 128;

    {   // stage folded with pad swizzle
        const float4* F = reinterpret_cast<const float4*>(folded);
        FS[t + (t >> 5)] = F[t];
        int j = t + 256;
        FS[j + (j >> 5)] = F[j];
    }
    int col = 0;
    if (t < 128) {
        float4 ce = reinterpret_cast<const float4*>(coor)[eb0 + t];
        TSx[t] = ftanh(ce.x); TSy[t] = ftanh(ce.y);
        TSz[t] = ftanh(ce.z); TSw[t] = ftanh(ce.w);
        col = idx[E_ + eb0 + t];
        float ex = ce.x + ce.z, ey = ce.y + ce.w;
        float sx = __shfl(ex, 0), sy = __shfl(ey, 0);  // wave = row here
        float att = 0.f;
        #pragma unroll
        for (int j = 0; j < 8; ++j) {
            float qj = fmaf(sy, Wq[8 + j], fmaf(sx, Wq[j], bq[j]));
            float kj = fmaf(ey, Wk[8 + j], fmaf(ex, Wk[j], bk[j]));
            att = fmaf(qj, kj, att);
        }
        COL[t] = col;
        ATT[t] = fabsf(att);
    }
    {   // zero-fill this block's 2 rows (replaces 64MB memset)
        float4 z = make_float4(0.f, 0.f, 0.f, 0.f);
        float4* orow = reinterpret_cast<float4*>(out + (size_t)row0 * N_);
        #pragma unroll
        for (int i = 0; i < 8; ++i) orow[i * 256 + t] = z;
    }
    __syncthreads();

    // ---- compute: 8 edges x 16 columns per thread ----
    const int eg = (t & 15) * 8;
    const int chunk = t >> 4;           // 0..15
    float4 xa = *reinterpret_cast<const float4*>(&TSx[eg]);
    float4 xb = *reinterpret_cast<const float4*>(&TSx[eg + 4]);
    float4 ya = *reinterpret_cast<const float4*>(&TSy[eg]);
    float4 yb = *reinterpret_cast<const float4*>(&TSy[eg + 4]);
    float4 za = *reinterpret_cast<const float4*>(&TSz[eg]);
    float4 zb = *reinterpret_cast<const float4*>(&TSz[eg + 4]);
    float4 wa = *reinterpret_cast<const float4*>(&TSw[eg]);
    float4 wb = *reinterpret_cast<const float4*>(&TSw[eg + 4]);
    const float4* Fp = &FS[chunk * 33];
    float ac0 = 0.f, ac1 = 0.f, ac2 = 0.f, ac3 = 0.f;
    float ac4 = 0.f, ac5 = 0.f, ac6 = 0.f, ac7 = 0.f;
    #define EVAL(tx_, ty_, tz_, tw_, ak) { \
        float u = fmaf(tw_, f0.w, fmaf(tz_, f0.z, fmaf(ty_, f0.y, fmaf(tx_, f0.x, f1.x)))); \
        float r = __builtin_amdgcn_rcpf(EXP2(u) + 1.0f); \
        float r2 = __builtin_amdgcn_rcpf(EXP2(fmaf(r, f1.y, f1.z)) + 1.0f); \
        ak = fmaf(r2, f1.w, ak); }
    #pragma unroll 4
    for (int i = 0; i < 16; ++i) {
        float4 f0 = Fp[2 * i];
        float4 f1 = Fp[2 * i + 1];
        EVAL(xa.x, ya.x, za.x, wa.x, ac0)
        EVAL(xa.y, ya.y, za.y, wa.y, ac1)
        EVAL(xa.z, ya.z, za.z, wa.z, ac2)
        EVAL(xa.w, ya.w, za.w, wa.w, ac3)
        EVAL(xb.x, yb.x, zb.x, wb.x, ac4)
        EVAL(xb.y, yb.y, zb.y, wb.y, ac5)
        EVAL(xb.z, yb.z, zb.z, wb.z, ac6)
        EVAL(xb.w, yb.w, zb.w, wb.w, ac7)
    }
    #undef EVAL
    *reinterpret_cast<float4*>(&ACC[chunk][eg])     = make_float4(ac0, ac1, ac2, ac3);
    *reinterpret_cast<float4*>(&ACC[chunk][eg + 4]) = make_float4(ac4, ac5, ac6, ac7);
    __syncthreads();

    // ---- write phase: waves 0,1 (wave = row) ----
    const int w = t >> 6, lane = t & 63;
    if (w < 2) {
        float val = swp[0];
        #pragma unroll
        for (int c = 0; c < 16; ++c) val += ACC[c][t];
        val = fmaxf(val, 0.f);

        size_t p = (size_t)(row0 + w) * N_ + col;
        float g = geo[p], an = ang[p];

        const int rb = w * 64;
        unsigned long long m = 0;
        float asum = 0.f;
        #pragma unroll 8
        for (int j4 = 0; j4 < 16; ++j4) {
            int4   c4 = *reinterpret_cast<const int4*>(&COL[rb + 4 * j4]);
            float4 a4 = *reinterpret_cast<const float4*>(&ATT[rb + 4 * j4]);
            m |= (unsigned long long)(c4.x == col) << (4 * j4 + 0);
            m |= (unsigned long long)(c4.y == col) << (4 * j4 + 1);
            m |= (unsigned long long)(c4.z == col) << (4 * j4 + 2);
            m |= (unsigned long long)(c4.w == col) << (4 * j4 + 3);
            asum += (c4.x == col) ? a4.x : 0.f;
            asum += (c4.y == col) ? a4.y : 0.f;
            asum += (c4.z == col) ? a4.z : 0.f;
            asum += (c4.w == col) ? a4.w : 0.f;
        }
        bool leader = ((m & ((1ull << lane) - 1ull)) == 0ull);

        float vsum = val;
        unsigned long long m2 = m & ~(1ull << lane);
        while (__any(m2 != 0ull)) {
            unsigned long long pick = m2 ? m2 : 1ull;
            int j = __ffsll(pick) - 1;
            float bv = __shfl(val, j);
            if (m2) { vsum += bv; m2 &= m2 - 1; }
        }
        if (leader) {
            out[p] = vsum * __expf(-asum * g) * an;
        }
    }
}

extern "C" void kernel_launch(void* const* d_in, const int* in_sizes, int n_in,
                              void* d_out, int out_size, void* d_ws, size_t ws_size,
                              hipStream_t stream)
{
    const float* coor  = (const float*)d_in[1];
    const int*   idx   = (const int*)d_in[2];
    const float* geo   = (const float*)d_in[3];
    const float* ang   = (const float*)d_in[4];
    const float* W0    = (const float*)d_in[5];
    const float* b0    = (const float*)d_in[6];
    const float* W1    = (const float*)d_in[7];
    const float* b1    = (const float*)d_in[8];
    const float* gamma = (const float*)d_in[9];
    const float* beta  = (const float*)d_in[10];
    const float* W2    = (const float*)d_in[11];
    const float* b2    = (const float*)d_in[12];
    const float* Wq    = (const float*)d_in[13];
    const float* bq    = (const float*)d_in[14];
    const float* Wk    = (const float*)d_in[15];
    const float* bk    = (const float*)d_in[16];

    float* ws     = (float*)d_ws;
    float* swp    = ws;              // 1
    float* W01g   = ws + 256;        // 1280 (5 x 256, TL2E-prescaled)
    float* folded = ws + 2048;       // 2048
    float* part   = ws + 8192;       // 32 x 512 floats (zeroed by prep2)

    prep2_kernel<<<8, 256, 0, stream>>>(W0, b0, W1, b1, W2, b2, W01g, swp, part);
    stats_kernel<<<E_ / 128, 256, 0, stream>>>(coor, W01g, part);
    fold_kernel<<<1, 256, 0, stream>>>(part, W01g, gamma, beta, W2, folded);
    edge_kernel<<<N_ / 2, 256, 0, stream>>>(coor, idx, folded, swp,
                                            Wq, bq, Wk, bk, geo, ang, (float*)d_out);
}